// Round 5
// baseline (178.428 us; speedup 1.0000x reference)
//
#include <hip/hip_runtime.h>
#include <hip/hip_bf16.h>
#include <math.h>
#include <float.h>

// Problem constants (x: [8192,128] f32, n_images=2)
static constexpr int NN    = 8192;
static constexpr int DD    = 128;
static constexpr int PP    = 4096;
static constexpr int NBLK2 = 512;            // 64 strip-pairs x 8 blocks
static constexpr int NC    = NBLK2 * 4 * 2;  // 2 cands per wave = 4096

struct Cand { float v; unsigned idx; };

using short8 = __attribute__((ext_vector_type(8))) short;
using f32x4  = __attribute__((ext_vector_type(4))) float;

typedef const __attribute__((address_space(1))) unsigned int* gas_uint;
typedef __attribute__((address_space(3))) unsigned int* las_uint;

// async 16B/lane global->LDS DMA; LDS dest = wave-uniform base + lane*16.
__device__ __forceinline__ void dma16(const void* g, const void* l) {
    __builtin_amdgcn_global_load_lds(
        (gas_uint)(unsigned long long)g,
        (las_uint)(unsigned)(unsigned long long)l, 16, 0, 0);
}

__device__ __forceinline__ unsigned pk2(float lo, float hi) {
    unsigned a = (unsigned)__builtin_bit_cast(unsigned short, __float2bfloat16(lo));
    unsigned b = (unsigned)__builtin_bit_cast(unsigned short, __float2bfloat16(hi));
    return a | (b << 16);
}

__device__ __forceinline__ void push1(float& v1, unsigned& i1, float& v2, unsigned& i2,
                                      float w, unsigned j) {
    if (w > v1) { v2 = v1; i2 = i1; v1 = w; i1 = j; }
    else if (w > v2) { v2 = w; i2 = j; }
}

__device__ __forceinline__ void merge2(float& v1, unsigned& i1, float& v2, unsigned& i2,
                                       float w1, unsigned j1, float w2, unsigned j2) {
    if (w1 > v1) {
        float nv2; unsigned ni2;
        if (v1 >= w2) { nv2 = v1; ni2 = i1; } else { nv2 = w2; ni2 = j2; }
        v1 = w1; i1 = j1; v2 = nv2; i2 = ni2;
    } else if (w1 > v2) {
        v2 = w1; i2 = j1;
    }
}

// ---- kernel 0: x -> bf16 with per-row K-chunk swizzle (chunk c stored at
// c^(r&7)) + sim_self in double ----
__global__ __launch_bounds__(256) void k_prep(const float* __restrict__ x,
                                              unsigned short* __restrict__ xb,
                                              double* __restrict__ ss) {
    const int tid = threadIdx.x;
    if (blockIdx.x < 512) {
        int g = blockIdx.x * 256 + tid;   // chunk id 0..131071 (8 floats each)
        int r = g >> 4, c = g & 15;
        const float4* s = (const float4*)(x + (size_t)g * 8);
        float4 f0 = s[0], f1 = s[1];
        uint4 o = {pk2(f0.x, f0.y), pk2(f0.z, f0.w), pk2(f1.x, f1.y), pk2(f1.z, f1.w)};
        *(uint4*)((char*)xb + (size_t)r * 256 + ((c ^ (r & 7)) * 16)) = o;
    } else {
        int b = blockIdx.x - 512;          // 0..63
        const int wv = tid >> 6, lane = tid & 63;
        #pragma unroll 4
        for (int u = 0; u < 16; ++u) {
            int p = b * 64 + wv * 16 + u;  // 0..4095
            const float* a  = x + (size_t)p * DD;
            const float* bb = a + DD;
            double s = (double)a[lane] * (double)bb[lane]
                     + (double)a[lane + 64] * (double)bb[lane + 64];
            #pragma unroll
            for (int off = 32; off >= 1; off >>= 1) s += __shfl_down(s, off);
            if (lane == 0) ss[p] = s;
        }
    }
}

// ---- kernel 1: barrier-free MFMA sweep. Block = (strip-pair, chunk of 65
// visits). A-strip (64 rows) fragments in registers; wave-private B slices
// (32 cols) double-buffered in LDS via contiguous DMA + vmcnt pipelining ----
__global__ __launch_bounds__(256, 2) void k_top2(const unsigned short* __restrict__ xb,
                                                 Cand* __restrict__ cands) {
    __shared__ __align__(16) char lds[4][2][8192];   // [wave][dbuf][32 rows x 256B]

    const int tid  = threadIdx.x;
    const int wv   = tid >> 6;
    const int lane = tid & 63;
    const int quad = lane >> 4;
    const int r16  = lane & 15;
    const int k7   = r16 & 7;
    char* buf = (char*)lds[wv];

    const int p    = blockIdx.x >> 3;   // strip pair 0..63 -> strips {p, 127-p}
    const int sub  = blockIdx.x & 7;
    const int v0   = sub * 8;
    const int vend = (sub == 7) ? 65 : v0 + 8;
    const int s0 = p, s1 = 127 - p;
    const int L1 = 64 - (s0 >> 1);      // visits on strip s0

    // visit v -> (strip, tj)
    #define SI_OF(v) (((v) < L1) ? s0 : s1)
    #define TJ_OF(v) (((v) < L1) ? (s0 >> 1) + (v) : (s1 >> 1) + ((v) - L1))

    // prologue: stage visit v0 into slot 0 (this wave's 32 B-rows, contiguous 8KB)
    {
        const char* g = (const char*)xb + ((size_t)TJ_OF(v0) * 128 + wv * 32) * 256;
        #pragma unroll
        for (int t = 0; t < 8; ++t)
            dma16(g + t * 1024 + (size_t)lane * 16, buf + t * 1024);
    }

    short8 af[4][4];     // A fragments [s][mi], reused across the sweep
    int cur_si = -1;

    float v1 = -INFINITY, v2 = -INFINITY;
    unsigned i1 = 0, i2 = 0;

    for (int v = v0; v < vend; ++v) {
        const int cur = (v - v0) & 1;
        const int si  = SI_OF(v);
        const int tj  = TJ_OF(v);

        if (si != cur_si) {   // (re)load A fragments from global (<=2x per block)
            cur_si = si;
            const char* arow = (const char*)xb + ((size_t)si * 64 + r16) * 256;
            #pragma unroll
            for (int s = 0; s < 4; ++s)
                #pragma unroll
                for (int mi = 0; mi < 4; ++mi)
                    af[s][mi] = *(const short8*)(arow + (size_t)(mi * 16) * 256
                                                 + ((4 * s + quad) ^ k7) * 16);
        }

        if (v + 1 < vend) {   // prefetch next visit's B slice into other slot
            const char* g = (const char*)xb
                          + ((size_t)TJ_OF(v + 1) * 128 + wv * 32) * 256;
            char* nb = buf + (1 - cur) * 8192;
            #pragma unroll
            for (int t = 0; t < 8; ++t)
                dma16(g + t * 1024 + (size_t)lane * 16, nb + t * 1024);
            // wait for everything older than the 8 just-issued DMAs
            asm volatile("s_waitcnt vmcnt(8)" ::: "memory");
        } else {
            asm volatile("s_waitcnt vmcnt(0)" ::: "memory");
        }

        const char* cb = buf + cur * 8192;
        short8 bfr[2][4];
        #pragma unroll
        for (int nj = 0; nj < 2; ++nj)
            #pragma unroll
            for (int s = 0; s < 4; ++s)
                bfr[nj][s] = *(const short8*)(cb + (nj * 16 + r16) * 256
                                              + ((4 * s + quad) ^ k7) * 16);

        #pragma unroll
        for (int mi = 0; mi < 4; ++mi) {
            #pragma unroll
            for (int nj = 0; nj < 2; ++nj) {
                f32x4 a = __builtin_amdgcn_mfma_f32_16x16x32_bf16(
                    af[0][mi], bfr[nj][0], (f32x4){0.f, 0.f, 0.f, 0.f}, 0, 0, 0);
                #pragma unroll
                for (int s = 1; s < 4; ++s)
                    a = __builtin_amdgcn_mfma_f32_16x16x32_bf16(
                        af[s][mi], bfr[nj][s], a, 0, 0, 0);
                // C/D layout: col = lane&15, row = quad*4 + reg
                int gj  = tj * 128 + wv * 32 + nj * 16 + r16;
                int gib = si * 64 + mi * 16 + quad * 4;
                #pragma unroll
                for (int reg = 0; reg < 4; ++reg) {
                    int gi = gib + reg;
                    if (gi < gj)
                        push1(v1, i1, v2, i2, a[reg], (unsigned)(gi * NN + gj));
                }
            }
        }
    }
    #undef SI_OF
    #undef TJ_OF

    // per-wave top-2 reduction, no cross-wave sync needed
    #pragma unroll
    for (int off = 32; off >= 1; off >>= 1) {
        float    w1 = __shfl_down(v1, off);
        unsigned j1 = (unsigned)__shfl_down((int)i1, off);
        float    w2 = __shfl_down(v2, off);
        unsigned j2 = (unsigned)__shfl_down((int)i2, off);
        merge2(v1, i1, v2, i2, w1, j1, w2, j2);
    }
    if (lane == 0) {
        cands[(blockIdx.x * 4 + wv) * 2]     = {v1, i1};
        cands[(blockIdx.x * 4 + wv) * 2 + 1] = {v2, i2};
    }
}

// ---- kernel 2: approx top-2 -> exact recheck (double) -> final mean ----
__global__ __launch_bounds__(256) void k_final(const float* __restrict__ x,
                                               const double* __restrict__ ss,
                                               const Cand* __restrict__ cands,
                                               float* __restrict__ out) {
    __shared__ float redv[8];
    __shared__ float s_thresh;
    __shared__ int cnt;
    __shared__ unsigned qidx[128];
    __shared__ double qex[128];
    __shared__ double sd1, sd2;
    __shared__ unsigned stopi;
    __shared__ double sacc[256];

    const int tid  = threadIdx.x;
    const int wv   = tid >> 6;
    const int lane = tid & 63;
    if (tid == 0) cnt = 0;

    // Phase A: approx global top-2 VALUES
    float v1 = -INFINITY, v2 = -INFINITY;
    for (int e = tid; e < NC; e += 256) {
        float v = cands[e].v;
        if (v > v1) { v2 = v1; v1 = v; }
        else if (v > v2) v2 = v;
    }
    #pragma unroll
    for (int off = 32; off >= 1; off >>= 1) {
        float w1 = __shfl_down(v1, off);
        float w2 = __shfl_down(v2, off);
        if (w1 > v1) { v2 = (v1 >= w2) ? v1 : w2; v1 = w1; }
        else if (w1 > v2) v2 = w1;
    }
    if (lane == 0) { redv[wv * 2] = v1; redv[wv * 2 + 1] = v2; }
    __syncthreads();
    if (tid == 0) {
        float a1 = -INFINITY, a2 = -INFINITY;
        for (int e = 0; e < 8; ++e) {
            float v = redv[e];
            if (v > a1) { a2 = a1; a1 = v; }
            else if (v > a2) a2 = v;
        }
        s_thresh = a2 - 1.0f;   // margin >> bf16 dot-product error bound (~0.1)
    }
    __syncthreads();
    const float thresh = s_thresh;

    // Phase B: gather all candidates within margin of approx top-2
    for (int e = tid; e < NC; e += 256) {
        if (cands[e].v >= thresh) {
            int k = atomicAdd(&cnt, 1);
            if (k < 128) qidx[k] = cands[e].idx;
        }
    }
    __syncthreads();
    const int n = cnt < 128 ? cnt : 128;

    // Phase C: exact double dot per qualifying candidate (one wave each)
    for (int c = wv; c < n; c += 4) {
        unsigned idx = qidx[c];
        unsigned gi = idx >> 13;
        unsigned gj = idx & 8191;
        const float* pa = x + (size_t)gi * DD;
        const float* pb = x + (size_t)gj * DD;
        double s = (double)pa[lane] * (double)pb[lane]
                 + (double)pa[lane + 64] * (double)pb[lane + 64];
        #pragma unroll
        for (int off = 32; off >= 1; off >>= 1) s += __shfl_down(s, off);
        if (lane == 0) qex[c] = s;
    }
    __syncthreads();

    // Phase D: exact top-2 over rechecked candidates
    if (tid == 0) {
        double d1 = -DBL_MAX, d2 = -DBL_MAX;
        unsigned bi = 0;
        for (int c = 0; c < n; ++c) {
            double v = qex[c];
            if (v > d1) { d2 = d1; d1 = v; bi = qidx[c]; }
            else if (v > d2) d2 = v;
        }
        sd1 = d1; sd2 = d2; stopi = bi;
    }
    __syncthreads();

    const double top1 = sd1, top2 = sd2;
    const unsigned topi = stopi;

    // Phase E: mean(sim_oth / sim_self)
    double acc = 0.0;
    for (int p = tid; p < PP; p += 256) {
        unsigned selfidx = (unsigned)(p * NN + p + 1);
        double so = (topi == selfidx) ? top2 : top1;
        acc += so / ss[p];
    }
    sacc[tid] = acc;
    __syncthreads();
    for (int s = 128; s >= 1; s >>= 1) {
        if (tid < s) sacc[tid] += sacc[tid + s];
        __syncthreads();
    }
    if (tid == 0) out[0] = (float)(sacc[0] / (double)PP);
}

extern "C" void kernel_launch(void* const* d_in, const int* in_sizes, int n_in,
                              void* d_out, int out_size, void* d_ws, size_t ws_size,
                              hipStream_t stream) {
    (void)in_sizes; (void)n_in; (void)out_size; (void)ws_size;
    const float* x = (const float*)d_in[0];
    float* out = (float*)d_out;

    double* ss  = (double*)d_ws;                                  // 32 KB
    Cand* cands = (Cand*)((char*)d_ws + 32768);                   // 32 KB
    unsigned short* xb = (unsigned short*)((char*)d_ws + 131072); // 2 MB

    k_prep<<<576, 256, 0, stream>>>(x, xb, ss);
    k_top2<<<NBLK2, 256, 0, stream>>>(xb, cands);
    k_final<<<1, 256, 0, stream>>>(x, ss, cands, out);
}

// Round 7
// 176.733 us; speedup vs baseline: 1.0096x; 1.0096x over previous
//
#include <hip/hip_runtime.h>
#include <hip/hip_bf16.h>
#include <math.h>
#include <float.h>

// Problem constants (x: [8192,128] f32, n_images=2)
static constexpr int NN   = 8192;
static constexpr int DD   = 128;
static constexpr int PP   = 4096;
static constexpr int TT   = 64;                 // 128-row tiles per dim
static constexpr int NBLK = TT * (TT + 1) / 2;  // 2080 tile-pair blocks
static constexpr int NC   = NBLK * 2;           // 2 cands per block = 4160

struct Cand { float v; unsigned idx; };

using short8 = __attribute__((ext_vector_type(8))) short;
using f32x4  = __attribute__((ext_vector_type(4))) float;

__device__ __forceinline__ unsigned pk2(float lo, float hi) {
    unsigned a = (unsigned)__builtin_bit_cast(unsigned short, __float2bfloat16(lo));
    unsigned b = (unsigned)__builtin_bit_cast(unsigned short, __float2bfloat16(hi));
    return a | (b << 16);
}

__device__ __forceinline__ void push1(float& v1, unsigned& i1, float& v2, unsigned& i2,
                                      float w, unsigned j) {
    if (w > v1) { v2 = v1; i2 = i1; v1 = w; i1 = j; }
    else if (w > v2) { v2 = w; i2 = j; }
}

__device__ __forceinline__ void merge2(float& v1, unsigned& i1, float& v2, unsigned& i2,
                                       float w1, unsigned j1, float w2, unsigned j2) {
    if (w1 > v1) {
        float nv2; unsigned ni2;
        if (v1 >= w2) { nv2 = v1; ni2 = i1; } else { nv2 = w2; ni2 = j2; }
        v1 = w1; i1 = j1; v2 = nv2; i2 = ni2;
    } else if (w1 > v2) {
        v2 = w1; i2 = j1;
    }
}

// ---- kernel 0: pack x into MFMA-fragment-tiled bf16 layout + sim_self ----
// Group g = 16 rows. Layout: byte offset = g*4096 + c*256 + rloc*16 where
// c = 16B k-chunk (16 per row), rloc = row within group. A wave fragment
// (group g, K-step s) is then xq + g*4096 + s*1024 + lane*16  (c = s*4+quad,
// k = s*32 + quad*8 + j -- the verified A/B fragment convention).
__global__ __launch_bounds__(256) void k_prep(const float* __restrict__ x,
                                              char* __restrict__ xq,
                                              double* __restrict__ ss) {
    const int tid = threadIdx.x;
    if (blockIdx.x < 512) {
        int gg   = blockIdx.x * 256 + tid;   // 0..131071, one 16B output each
        int grp  = gg >> 8;                  // 0..511  (256 chunks per group)
        int c    = (gg >> 4) & 15;           // 0..15
        int rloc = gg & 15;                  // 0..15
        int r    = grp * 16 + rloc;          // 0..8191
        const float4* s = (const float4*)(x + (size_t)r * DD + c * 8);
        float4 f0 = s[0], f1 = s[1];
        uint4 o = {pk2(f0.x, f0.y), pk2(f0.z, f0.w), pk2(f1.x, f1.y), pk2(f1.z, f1.w)};
        *(uint4*)(xq + (size_t)gg * 16) = o;   // contiguous, fully coalesced
    } else {
        int b = blockIdx.x - 512;          // 0..63
        const int wv = tid >> 6, lane = tid & 63;
        #pragma unroll 4
        for (int u = 0; u < 16; ++u) {
            int p = b * 64 + wv * 16 + u;  // 0..4095
            const float* a  = x + (size_t)p * DD;
            const float* bb = a + DD;
            double s = (double)a[lane] * (double)bb[lane]
                     + (double)a[lane + 64] * (double)bb[lane + 64];
            #pragma unroll
            for (int off = 32; off >= 1; off >>= 1) s += __shfl_down(s, off);
            if (lane == 0) ss[p] = s;
        }
    }
}

// ---- kernel 1: LDS-free, barrier-free (K-loop) MFMA top-2. Block = 128x128
// tile pair; wave = 64x64 quadrant. B fragments (16) resident in VGPRs, A
// fragments rotated with 1-deep prefetch. All fragment loads are coalesced
// global_load_dwordx4 (1KB/wave) from the fragment-tiled xq. ----
__global__ __launch_bounds__(256, 4) void k_top2(const char* __restrict__ xq,
                                                 Cand* __restrict__ cands) {
    __shared__ float sv1[4], sv2[4];
    __shared__ unsigned si1[4], si2[4];

    // decode linear block id -> (ti, tj), ti <= tj
    int rem = blockIdx.x;
    int ti = 0;
    while (rem >= TT - ti) { rem -= (TT - ti); ++ti; }
    int tj = ti + rem;

    const int tid  = threadIdx.x;
    const int wv   = tid >> 6;
    const int lane = tid & 63;
    const int quad = lane >> 4;
    const int r16  = lane & 15;
    const int wm   = wv >> 1;
    const int wn   = wv & 1;

    const char* fb = xq + (size_t)lane * 16;   // per-lane fragment base
    const int jg = tj * 8 + wn * 4;            // first B row-group (16 cols each)
    const int ig = ti * 8 + wm * 4;            // first A row-group

    // B fragments resident: [gn][K-step s]
    short8 bf[4][4];
    #pragma unroll
    for (int gn = 0; gn < 4; ++gn)
        #pragma unroll
        for (int s = 0; s < 4; ++s)
            bf[gn][s] = *(const short8*)(fb + (size_t)(jg + gn) * 4096 + s * 1024);

    float v1 = -INFINITY, v2 = -INFINITY;
    unsigned i1 = 0, i2 = 0;

    short8 am[4], an[4];
    #pragma unroll
    for (int s = 0; s < 4; ++s)
        am[s] = *(const short8*)(fb + (size_t)ig * 4096 + s * 1024);

    #pragma unroll
    for (int gm = 0; gm < 4; ++gm) {
        if (gm < 3) {   // prefetch next A group (compile-time guard)
            #pragma unroll
            for (int s = 0; s < 4; ++s)
                an[s] = *(const short8*)(fb + (size_t)(ig + gm + 1) * 4096 + s * 1024);
        }
        #pragma unroll
        for (int gn = 0; gn < 4; ++gn) {
            f32x4 a = __builtin_amdgcn_mfma_f32_16x16x32_bf16(
                am[0], bf[gn][0], (f32x4){0.f, 0.f, 0.f, 0.f}, 0, 0, 0);
            #pragma unroll
            for (int s = 1; s < 4; ++s)
                a = __builtin_amdgcn_mfma_f32_16x16x32_bf16(
                    am[s], bf[gn][s], a, 0, 0, 0);
            // C/D layout: col = lane&15, row = quad*4 + reg
            int gj  = (jg + gn) * 16 + r16;
            int gib = (ig + gm) * 16 + quad * 4;
            #pragma unroll
            for (int reg = 0; reg < 4; ++reg) {
                int gi = gib + reg;
                if (gi < gj)
                    push1(v1, i1, v2, i2, a[reg], (unsigned)(gi * NN + gj));
            }
        }
        #pragma unroll
        for (int s = 0; s < 4; ++s) am[s] = an[s];
    }

    // wave top-2 reduction, then block reduce via tiny LDS
    #pragma unroll
    for (int off = 32; off >= 1; off >>= 1) {
        float    w1 = __shfl_down(v1, off);
        unsigned j1 = (unsigned)__shfl_down((int)i1, off);
        float    w2 = __shfl_down(v2, off);
        unsigned j2 = (unsigned)__shfl_down((int)i2, off);
        merge2(v1, i1, v2, i2, w1, j1, w2, j2);
    }
    if (lane == 0) { sv1[wv] = v1; si1[wv] = i1; sv2[wv] = v2; si2[wv] = i2; }
    __syncthreads();
    if (tid == 0) {
        for (int w = 1; w < 4; ++w)
            merge2(v1, i1, v2, i2, sv1[w], si1[w], sv2[w], si2[w]);
        cands[blockIdx.x * 2]     = {v1, i1};
        cands[blockIdx.x * 2 + 1] = {v2, i2};
    }
}

// ---- kernel 2: approx top-2 -> exact recheck (double) -> final mean ----
__global__ __launch_bounds__(256) void k_final(const float* __restrict__ x,
                                               const double* __restrict__ ss,
                                               const Cand* __restrict__ cands,
                                               float* __restrict__ out) {
    __shared__ float redv[8];
    __shared__ float s_thresh;
    __shared__ int cnt;
    __shared__ unsigned qidx[128];
    __shared__ double qex[128];
    __shared__ double sd1, sd2;
    __shared__ unsigned stopi;
    __shared__ double sacc[256];

    const int tid  = threadIdx.x;
    const int wv   = tid >> 6;
    const int lane = tid & 63;
    if (tid == 0) cnt = 0;

    // Phase A: approx global top-2 VALUES
    float v1 = -INFINITY, v2 = -INFINITY;
    for (int e = tid; e < NC; e += 256) {
        float v = cands[e].v;
        if (v > v1) { v2 = v1; v1 = v; }
        else if (v > v2) v2 = v;
    }
    #pragma unroll
    for (int off = 32; off >= 1; off >>= 1) {
        float w1 = __shfl_down(v1, off);
        float w2 = __shfl_down(v2, off);
        if (w1 > v1) { v2 = (v1 >= w2) ? v1 : w2; v1 = w1; }
        else if (w1 > v2) v2 = w1;
    }
    if (lane == 0) { redv[wv * 2] = v1; redv[wv * 2 + 1] = v2; }
    __syncthreads();
    if (tid == 0) {
        float a1 = -INFINITY, a2 = -INFINITY;
        for (int e = 0; e < 8; ++e) {
            float v = redv[e];
            if (v > a1) { a2 = a1; a1 = v; }
            else if (v > a2) a2 = v;
        }
        s_thresh = a2 - 1.0f;   // margin >> bf16 dot-product error bound (~0.1)
    }
    __syncthreads();
    const float thresh = s_thresh;

    // Phase B: gather all candidates within margin of approx top-2
    for (int e = tid; e < NC; e += 256) {
        if (cands[e].v >= thresh) {
            int k = atomicAdd(&cnt, 1);
            if (k < 128) qidx[k] = cands[e].idx;
        }
    }
    __syncthreads();
    const int n = cnt < 128 ? cnt : 128;

    // Phase C: exact double dot per qualifying candidate (one wave each)
    for (int c = wv; c < n; c += 4) {
        unsigned idx = qidx[c];
        unsigned gi = idx >> 13;
        unsigned gj = idx & 8191;
        const float* pa = x + (size_t)gi * DD;
        const float* pb = x + (size_t)gj * DD;
        double s = (double)pa[lane] * (double)pb[lane]
                 + (double)pa[lane + 64] * (double)pb[lane + 64];
        #pragma unroll
        for (int off = 32; off >= 1; off >>= 1) s += __shfl_down(s, off);
        if (lane == 0) qex[c] = s;
    }
    __syncthreads();

    // Phase D: exact top-2 over rechecked candidates
    if (tid == 0) {
        double d1 = -DBL_MAX, d2 = -DBL_MAX;
        unsigned bi = 0;
        for (int c = 0; c < n; ++c) {
            double v = qex[c];
            if (v > d1) { d2 = d1; d1 = v; bi = qidx[c]; }
            else if (v > d2) d2 = v;
        }
        sd1 = d1; sd2 = d2; stopi = bi;
    }
    __syncthreads();

    const double top1 = sd1, top2 = sd2;
    const unsigned topi = stopi;

    // Phase E: mean(sim_oth / sim_self)
    double acc = 0.0;
    for (int p = tid; p < PP; p += 256) {
        unsigned selfidx = (unsigned)(p * NN + p + 1);
        double so = (topi == selfidx) ? top2 : top1;
        acc += so / ss[p];
    }
    sacc[tid] = acc;
    __syncthreads();
    for (int s = 128; s >= 1; s >>= 1) {
        if (tid < s) sacc[tid] += sacc[tid + s];
        __syncthreads();
    }
    if (tid == 0) out[0] = (float)(sacc[0] / (double)PP);
}

extern "C" void kernel_launch(void* const* d_in, const int* in_sizes, int n_in,
                              void* d_out, int out_size, void* d_ws, size_t ws_size,
                              hipStream_t stream) {
    (void)in_sizes; (void)n_in; (void)out_size; (void)ws_size;
    const float* x = (const float*)d_in[0];
    float* out = (float*)d_out;

    double* ss  = (double*)d_ws;                 // 32 KB
    Cand* cands = (Cand*)((char*)d_ws + 32768);  // ~33 KB
    char* xq    = (char*)d_ws + 131072;          // 2 MB fragment-tiled bf16

    k_prep<<<576, 256, 0, stream>>>(x, xq, ss);
    k_top2<<<NBLK, 256, 0, stream>>>(xq, cands);
    k_final<<<1, 256, 0, stream>>>(x, ss, cands, out);
}